// Round 1
// baseline (336.750 us; speedup 1.0000x reference)
//
#include <hip/hip_runtime.h>
#include <hip/hip_bf16.h>
#include <stdint.h>

typedef __bf16 bf16;
typedef __attribute__((ext_vector_type(8))) short short8;
typedef __attribute__((ext_vector_type(4))) float f32x4;
typedef __attribute__((ext_vector_type(4))) bf16 bf16x4;

#define DIM 512
#define NBATCH 8
#define SEQ 2048
#define MTOT (NBATCH * SEQ)

// async global->LDS, 16B per lane; LDS dest must be wave-uniform base + lane*16
__device__ __forceinline__ void gld_lds16(const bf16* g, bf16* l) {
    __builtin_amdgcn_global_load_lds(
        (const __attribute__((address_space(1))) void*)g,
        (__attribute__((address_space(3))) void*)l,
        16, 0, 0);
}

// ---------------------------------------------------------------------------
// C = alpha * (A @ Bt^T) + bias  — m97-style bt-GEMM.
// A:  [M][K] bf16 row-major (M = gridDim.y*128)
// Bt: [N][K] bf16 row-major (N = gridDim.x*128)
// MODE 0: C bf16 row-major [M][N] (+z*sC)
// MODE 1: C bf16 transposed per batch: Vt[b][col][n], b=row>>11, n=row&2047
// MODE 2: C fp32 row-major [M][N]
// ---------------------------------------------------------------------------
template <int MODE>
__global__ __launch_bounds__(256) void gemm_bt(
    const bf16* __restrict__ A, const bf16* __restrict__ Bt,
    void* __restrict__ Cv, const float* __restrict__ bias,
    int N, int K, long long sA, long long sB, long long sC, float alpha)
{
    __shared__ bf16 As[128 * 32];
    __shared__ bf16 Bs[128 * 32];

    const int tid  = threadIdx.x;
    const int lane = tid & 63;
    const int w    = tid >> 6;        // wave 0..3
    const int wr   = w >> 1;          // wave row 0..1  (64-row stripes)
    const int wc   = w & 1;           // wave col 0..1  (64-col stripes)
    const int lm   = lane & 15;       // frag row/col
    const int lk   = lane >> 4;       // frag k-group (0..3)
    const int srow = lane >> 2;       // staging: 4 lanes per row
    const int scol = (lane & 3) * 8;  // staging: 8 bf16 = 16B per lane

    const size_t z = blockIdx.z;
    const bf16* Ag = A + z * (size_t)sA + (size_t)(blockIdx.y * 128) * K;
    const bf16* Bg = Bt + z * (size_t)sB + (size_t)(blockIdx.x * 128) * K;

    f32x4 acc[4][4];
#pragma unroll
    for (int i = 0; i < 4; ++i)
#pragma unroll
        for (int j = 0; j < 4; ++j)
            acc[i][j] = (f32x4){0.f, 0.f, 0.f, 0.f};

    for (int kb = 0; kb < K; kb += 32) {
#pragma unroll
        for (int t = 0; t < 2; ++t) {
            const int c = w * 2 + t;          // chunk 0..7 (16 rows each)
            const int r = c * 16 + srow;
            gld_lds16(Ag + (size_t)r * K + kb + scol, &As[r * 32 + scol]);
            gld_lds16(Bg + (size_t)r * K + kb + scol, &Bs[r * 32 + scol]);
        }
        __syncthreads();

        short8 fa[4], fb[4];
#pragma unroll
        for (int i = 0; i < 4; ++i)
            fa[i] = *(const short8*)&As[(wr * 64 + i * 16 + lm) * 32 + lk * 8];
#pragma unroll
        for (int j = 0; j < 4; ++j)
            fb[j] = *(const short8*)&Bs[(wc * 64 + j * 16 + lm) * 32 + lk * 8];
#pragma unroll
        for (int i = 0; i < 4; ++i)
#pragma unroll
            for (int j = 0; j < 4; ++j)
                acc[i][j] = __builtin_amdgcn_mfma_f32_16x16x32_bf16(
                    fa[i], fb[j], acc[i][j], 0, 0, 0);
        __syncthreads();
    }

    // Epilogue. C/D layout: col = lane&15, row = (lane>>4)*4 + reg  (m89/m91)
    const int orow0 = blockIdx.y * 128 + wr * 64;
    const int ocol0 = blockIdx.x * 128 + wc * 64;
#pragma unroll
    for (int i = 0; i < 4; ++i) {
#pragma unroll
        for (int j = 0; j < 4; ++j) {
            const int col = ocol0 + j * 16 + lm;
            const float bv = bias ? bias[col] : 0.0f;
#pragma unroll
            for (int r = 0; r < 4; ++r) {
                const int row = orow0 + i * 16 + lk * 4 + r;
                const float v = acc[i][j][r] * alpha + bv;
                if (MODE == 0) {
                    ((bf16*)Cv)[z * (size_t)sC + (size_t)row * N + col] = (bf16)v;
                } else if (MODE == 1) {
                    const int b = row >> 11, nn = row & 2047;
                    ((bf16*)Cv)[((size_t)b * DIM + col) * SEQ + nn] = (bf16)v;
                } else {
                    ((float*)Cv)[z * (size_t)sC + (size_t)row * N + col] = v;
                }
            }
        }
    }
}

// ---------------------------------------------------------------------------
// In-place row softmax on bf16 S [16384][2048]; fp32 math.
// ---------------------------------------------------------------------------
__global__ __launch_bounds__(256) void softmax_rows(bf16* __restrict__ S)
{
    const size_t row = blockIdx.x;
    bf16* p = S + row * SEQ;
    const int t = threadIdx.x;
    const int lane = t & 63, w = t >> 6;

    uint4 raw = ((uint4*)p)[t];          // 8 bf16 = 16B per thread
    bf16* pv = (bf16*)&raw;
    float v[8];
    float m = -1e30f;
#pragma unroll
    for (int i = 0; i < 8; ++i) { v[i] = (float)pv[i]; m = fmaxf(m, v[i]); }
#pragma unroll
    for (int o = 32; o > 0; o >>= 1) m = fmaxf(m, __shfl_xor(m, o));

    __shared__ float red[8];
    if (lane == 0) red[w] = m;
    __syncthreads();
    m = fmaxf(fmaxf(red[0], red[1]), fmaxf(red[2], red[3]));

    float s = 0.f;
#pragma unroll
    for (int i = 0; i < 8; ++i) { v[i] = __expf(v[i] - m); s += v[i]; }
#pragma unroll
    for (int o = 32; o > 0; o >>= 1) s += __shfl_xor(s, o);
    if (lane == 0) red[4 + w] = s;
    __syncthreads();
    const float inv = 1.0f / (red[4] + red[5] + red[6] + red[7]);

#pragma unroll
    for (int i = 0; i < 8; ++i) pv[i] = (bf16)(v[i] * inv);
    ((uint4*)p)[t] = raw;
}

// ---------------------------------------------------------------------------
// fp32 -> bf16, 4 elements/thread
// ---------------------------------------------------------------------------
__global__ __launch_bounds__(256) void cvt_f32_bf16(
    const float* __restrict__ x, bf16* __restrict__ o, int n4)
{
    const int i = blockIdx.x * 256 + threadIdx.x;
    if (i >= n4) return;
    const float4 v = ((const float4*)x)[i];
    bf16x4 b;
    b[0] = (bf16)v.x; b[1] = (bf16)v.y; b[2] = (bf16)v.z; b[3] = (bf16)v.w;
    ((bf16x4*)o)[i] = b;
}

// W [512][512] fp32 -> Wt [512][512] bf16 with Wt[o][i] = W[i][o]
__global__ __launch_bounds__(256) void transpose_w(
    const float* __restrict__ W, bf16* __restrict__ Wt)
{
    const int t = blockIdx.x * 256 + threadIdx.x;  // 262144 total
    const int o = t >> 9, i = t & 511;
    Wt[t] = (bf16)W[i * 512 + o];
}

// ---------------------------------------------------------------------------
extern "C" void kernel_launch(void* const* d_in, const int* in_sizes, int n_in,
                              void* d_out, int out_size, void* d_ws, size_t ws_size,
                              hipStream_t stream)
{
    const float* x  = (const float*)d_in[0];
    const float* Wq = (const float*)d_in[1];
    const float* bq = (const float*)d_in[2];
    const float* Wk = (const float*)d_in[3];
    const float* bk = (const float*)d_in[4];
    const float* Wv = (const float*)d_in[5];
    const float* bv = (const float*)d_in[6];
    const float* Wo = (const float*)d_in[7];
    const float* bo = (const float*)d_in[8];
    float* out = (float*)d_out;

    char* ws = (char*)d_ws;
    bf16* Xb  = (bf16*)(ws);              // 16384x512 bf16      (16 MB)
    bf16* Wtq = (bf16*)(ws + 16777216);   // 512x512 bf16 (transposed)
    bf16* Wtk = (bf16*)(ws + 17301504);
    bf16* Wtv = (bf16*)(ws + 17825792);
    bf16* Wto = (bf16*)(ws + 18350080);
    bf16* Q   = (bf16*)(ws + 18874368);   // 16384x512
    bf16* Kb  = (bf16*)(ws + 35651584);   // 16384x512
    bf16* Vt  = (bf16*)(ws + 52428800);   // [8][512][2048] (V transposed)
    bf16* S   = (bf16*)(ws + 69206016);   // [8][2048][2048]     (67 MB)
    bf16* Ctx = (bf16*)(ws + 136314880);  // 16384x512

    // prologue: bf16 conversions
    cvt_f32_bf16<<<8192, 256, 0, stream>>>(x, Xb, 2097152);
    transpose_w<<<1024, 256, 0, stream>>>(Wq, Wtq);
    transpose_w<<<1024, 256, 0, stream>>>(Wk, Wtk);
    transpose_w<<<1024, 256, 0, stream>>>(Wv, Wtv);
    transpose_w<<<1024, 256, 0, stream>>>(Wo, Wto);

    const float scale = 0.044194173824159216f;  // 512^-0.5

    // Q/K/V projections: M=16384, N=512, K=512
    gemm_bt<0><<<dim3(4, 128, 1), 256, 0, stream>>>(Xb, Wtq, Q,  bq, 512, 512, 0, 0, 0, 1.0f);
    gemm_bt<0><<<dim3(4, 128, 1), 256, 0, stream>>>(Xb, Wtk, Kb, bk, 512, 512, 0, 0, 0, 1.0f);
    gemm_bt<1><<<dim3(4, 128, 1), 256, 0, stream>>>(Xb, Wtv, Vt, bv, 512, 512, 0, 0, 0, 1.0f);

    // S = scale * Q @ K^T, per batch: M=N=2048, K=512
    gemm_bt<0><<<dim3(16, 16, 8), 256, 0, stream>>>(
        Q, Kb, S, nullptr, 2048, 512, 2048LL * 512, 2048LL * 512, 2048LL * 2048, scale);

    // P = softmax(S) in place
    softmax_rows<<<16384, 256, 0, stream>>>(S);

    // Ctx = P @ V, per batch: M=2048, N=512, K=2048 (Vt is the B^T operand)
    gemm_bt<0><<<dim3(4, 16, 8), 256, 0, stream>>>(
        S, Vt, Ctx, nullptr, 512, 2048, 2048LL * 2048, 512LL * 2048, 2048LL * 512, 1.0f);

    // Out = Ctx @ Wo^T + bo: M=16384, N=512, K=512, fp32 out
    gemm_bt<2><<<dim3(4, 128, 1), 256, 0, stream>>>(
        Ctx, Wto, out, bo, 512, 512, 0, 0, 0, 1.0f);
}

// Round 2
// 316.747 us; speedup vs baseline: 1.0632x; 1.0632x over previous
//
#include <hip/hip_runtime.h>
#include <hip/hip_bf16.h>
#include <stdint.h>

typedef __bf16 bf16;
typedef __attribute__((ext_vector_type(8))) short short8;
typedef __attribute__((ext_vector_type(4))) float f32x4;
typedef __attribute__((ext_vector_type(4))) bf16 bf16x4;

#define DIM 512
#define NBATCH 8
#define SEQ 2048
#define MTOT (NBATCH * SEQ)

// async global->LDS, 16B per lane; LDS dest must be wave-uniform base + lane*16
__device__ __forceinline__ void gld_lds16(const bf16* g, bf16* l) {
    __builtin_amdgcn_global_load_lds(
        (const __attribute__((address_space(1))) void*)g,
        (__attribute__((address_space(3))) void*)l,
        16, 0, 0);
}

// ---------------------------------------------------------------------------
// C = alpha * (A @ Bt^T) + bias  — m97-style bt-GEMM, 128x128 tile, BK=32.
// A:  [M][K] bf16 row-major;  Bt: [N][K] bf16 row-major.
// MODE 0: C bf16 row-major [M][N] (+z*sC)
// MODE 2: C fp32 row-major [M][N]
// MODE 3: QKV split epilogue: col<512 -> Q, <1024 -> K (row-major, stride 512),
//         else -> Vt[b][col-1024][n] (b=row>>11, n=row&2047). Cv = Q base;
//         K at Q+8388608 elems, Vt at Q+16777216 elems (contiguous ws layout).
// SWIZ: 1D grid, bz = g&7 (batch <-> XCD round-robin heuristic), then
//       r = g>>3: bx = r % gx, by = r / gx  (x-siblings consecutive per XCD).
// ---------------------------------------------------------------------------
template <int MODE, bool SWIZ>
__global__ __launch_bounds__(256) void gemm_bt(
    const bf16* __restrict__ A, const bf16* __restrict__ Bt,
    void* __restrict__ Cv, const float* __restrict__ bias,
    int N, int K, long long sA, long long sB, long long sC, float alpha,
    int gx)
{
    __shared__ bf16 As[128 * 32];
    __shared__ bf16 Bs[128 * 32];

    int bx, by, bz;
    if (SWIZ) {
        const unsigned g = blockIdx.x;
        bz = g & 7;
        const unsigned r = g >> 3;
        bx = r % (unsigned)gx;
        by = r / (unsigned)gx;
    } else {
        bx = blockIdx.x; by = blockIdx.y; bz = blockIdx.z;
    }

    const int tid  = threadIdx.x;
    const int lane = tid & 63;
    const int w    = tid >> 6;        // wave 0..3
    const int wr   = w >> 1;          // wave row 0..1  (64-row stripes)
    const int wc   = w & 1;           // wave col 0..1  (64-col stripes)
    const int lm   = lane & 15;       // frag row/col
    const int lk   = lane >> 4;       // frag k-group (0..3)
    const int srow = lane >> 2;       // staging: 4 lanes per row
    const int scol = (lane & 3) * 8;  // staging: 8 bf16 = 16B per lane

    const size_t z = bz;
    const bf16* Ag = A + z * (size_t)sA + (size_t)(by * 128) * K;
    const bf16* Bg = Bt + z * (size_t)sB + (size_t)(bx * 128) * K;

    f32x4 acc[4][4];
#pragma unroll
    for (int i = 0; i < 4; ++i)
#pragma unroll
        for (int j = 0; j < 4; ++j)
            acc[i][j] = (f32x4){0.f, 0.f, 0.f, 0.f};

    for (int kb = 0; kb < K; kb += 32) {
#pragma unroll
        for (int t = 0; t < 2; ++t) {
            const int c = w * 2 + t;          // chunk 0..7 (16 rows each)
            const int r = c * 16 + srow;
            gld_lds16(Ag + (size_t)r * K + kb + scol, &As[r * 32 + scol]);
            gld_lds16(Bg + (size_t)r * K + kb + scol, &Bs[r * 32 + scol]);
        }
        __syncthreads();

        short8 fa[4], fb[4];
#pragma unroll
        for (int i = 0; i < 4; ++i)
            fa[i] = *(const short8*)&As[(wr * 64 + i * 16 + lm) * 32 + lk * 8];
#pragma unroll
        for (int j = 0; j < 4; ++j)
            fb[j] = *(const short8*)&Bs[(wc * 64 + j * 16 + lm) * 32 + lk * 8];
#pragma unroll
        for (int i = 0; i < 4; ++i)
#pragma unroll
            for (int j = 0; j < 4; ++j)
                acc[i][j] = __builtin_amdgcn_mfma_f32_16x16x32_bf16(
                    fa[i], fb[j], acc[i][j], 0, 0, 0);
        __syncthreads();
    }

    // Epilogue. C/D layout: col = lane&15, row = (lane>>4)*4 + reg  (m89/m91)
    const int orow0 = by * 128 + wr * 64;
    const int ocol0 = bx * 128 + wc * 64;
#pragma unroll
    for (int i = 0; i < 4; ++i) {
#pragma unroll
        for (int j = 0; j < 4; ++j) {
            const int col = ocol0 + j * 16 + lm;
            const float bv = bias ? bias[col] : 0.0f;
#pragma unroll
            for (int r = 0; r < 4; ++r) {
                const int row = orow0 + i * 16 + lk * 4 + r;
                const float v = acc[i][j][r] * alpha + bv;
                if (MODE == 0) {
                    ((bf16*)Cv)[z * (size_t)sC + (size_t)row * N + col] = (bf16)v;
                } else if (MODE == 2) {
                    ((float*)Cv)[z * (size_t)sC + (size_t)row * N + col] = v;
                } else {  // MODE 3: QKV split
                    bf16* Qp = (bf16*)Cv;
                    if (col < 512) {
                        Qp[(size_t)row * 512 + col] = (bf16)v;
                    } else if (col < 1024) {
                        Qp[(size_t)8388608 + (size_t)row * 512 + (col - 512)] = (bf16)v;
                    } else {
                        const int b = row >> 11, nn = row & 2047;
                        Qp[(size_t)16777216 +
                           ((size_t)b * 512 + (col - 1024)) * 2048 + nn] = (bf16)v;
                    }
                }
            }
        }
    }
}

// ---------------------------------------------------------------------------
// In-place row softmax on bf16 S [16384][2048]; fp32 math.
// ---------------------------------------------------------------------------
__global__ __launch_bounds__(256) void softmax_rows(bf16* __restrict__ S)
{
    const size_t row = blockIdx.x;
    bf16* p = S + row * SEQ;
    const int t = threadIdx.x;
    const int lane = t & 63, w = t >> 6;

    uint4 raw = ((uint4*)p)[t];          // 8 bf16 = 16B per thread
    bf16* pv = (bf16*)&raw;
    float v[8];
    float m = -1e30f;
#pragma unroll
    for (int i = 0; i < 8; ++i) { v[i] = (float)pv[i]; m = fmaxf(m, v[i]); }
#pragma unroll
    for (int o = 32; o > 0; o >>= 1) m = fmaxf(m, __shfl_xor(m, o));

    __shared__ float red[8];
    if (lane == 0) red[w] = m;
    __syncthreads();
    m = fmaxf(fmaxf(red[0], red[1]), fmaxf(red[2], red[3]));

    float s = 0.f;
#pragma unroll
    for (int i = 0; i < 8; ++i) { v[i] = __expf(v[i] - m); s += v[i]; }
#pragma unroll
    for (int o = 32; o > 0; o >>= 1) s += __shfl_xor(s, o);
    if (lane == 0) red[4 + w] = s;
    __syncthreads();
    const float inv = 1.0f / (red[4] + red[5] + red[6] + red[7]);

#pragma unroll
    for (int i = 0; i < 8; ++i) pv[i] = (bf16)(v[i] * inv);
    ((uint4*)p)[t] = raw;
}

// ---------------------------------------------------------------------------
// fp32 -> bf16, 4 elements/thread
// ---------------------------------------------------------------------------
__global__ __launch_bounds__(256) void cvt_f32_bf16(
    const float* __restrict__ x, bf16* __restrict__ o, int n4)
{
    const int i = blockIdx.x * 256 + threadIdx.x;
    if (i >= n4) return;
    const float4 v = ((const float4*)x)[i];
    bf16x4 b;
    b[0] = (bf16)v.x; b[1] = (bf16)v.y; b[2] = (bf16)v.z; b[3] = (bf16)v.w;
    ((bf16x4*)o)[i] = b;
}

// ---------------------------------------------------------------------------
// Tiled transpose of all four 512x512 fp32 weights -> bf16, transposed.
// z = 0..2 -> Wcat rows [z*512, z*512+512); z = 3 -> Wto.
// 64x64 tile per block; LDS padded to 65 to kill write-phase bank conflicts.
// ---------------------------------------------------------------------------
__global__ __launch_bounds__(256) void transpose4(
    const float* __restrict__ Wq, const float* __restrict__ Wk,
    const float* __restrict__ Wv, const float* __restrict__ Wo,
    bf16* __restrict__ Wcat, bf16* __restrict__ Wto)
{
    __shared__ bf16 tile[64][65];
    const int widx = blockIdx.z;
    const float* W = (widx == 0) ? Wq : (widx == 1) ? Wk : (widx == 2) ? Wv : Wo;
    bf16* dst = (widx < 3) ? (Wcat + (size_t)widx * 512 * 512) : Wto;
    const int tx = blockIdx.x, ty = blockIdx.y;
    const int t0 = threadIdx.x;
#pragma unroll
    for (int it = 0; it < 16; ++it) {
        const int e = it * 256 + t0;
        const int r = e >> 6, c = e & 63;
        tile[r][c] = (bf16)W[(size_t)(ty * 64 + r) * 512 + tx * 64 + c];
    }
    __syncthreads();
#pragma unroll
    for (int it = 0; it < 16; ++it) {
        const int e = it * 256 + t0;
        const int o = e >> 6, i = e & 63;
        dst[(size_t)(tx * 64 + o) * 512 + ty * 64 + i] = tile[i][o];
    }
}

__global__ __launch_bounds__(256) void pack_bias(
    const float* __restrict__ bq, const float* __restrict__ bk,
    const float* __restrict__ bv, float* __restrict__ bcat)
{
    const int i = blockIdx.x * 256 + threadIdx.x;
    if (i >= 1536) return;
    bcat[i] = (i < 512) ? bq[i] : (i < 1024) ? bk[i - 512] : bv[i - 1024];
}

// ---------------------------------------------------------------------------
extern "C" void kernel_launch(void* const* d_in, const int* in_sizes, int n_in,
                              void* d_out, int out_size, void* d_ws, size_t ws_size,
                              hipStream_t stream)
{
    const float* x  = (const float*)d_in[0];
    const float* Wq = (const float*)d_in[1];
    const float* bq = (const float*)d_in[2];
    const float* Wk = (const float*)d_in[3];
    const float* bk = (const float*)d_in[4];
    const float* Wv = (const float*)d_in[5];
    const float* bv = (const float*)d_in[6];
    const float* Wo = (const float*)d_in[7];
    const float* bo = (const float*)d_in[8];
    float* out = (float*)d_out;

    char* ws = (char*)d_ws;
    bf16*  Xb   = (bf16*)(ws);              // 16384x512 bf16        (16 MB)
    bf16*  Wcat = (bf16*)(ws + 16777216);   // 1536x512 bf16 (Wq^T|Wk^T|Wv^T)
    bf16*  Wto  = (bf16*)(ws + 18350080);   // 512x512 bf16 (Wo^T)
    float* bcat = (float*)(ws + 18874368);  // 1536 fp32
    bf16*  Q    = (bf16*)(ws + 18882560);   // 16384x512   -- Q|K|Vt contiguous!
    bf16*  Kb   = (bf16*)(ws + 35659776);   // 16384x512
    bf16*  Vt   = (bf16*)(ws + 52436992);   // [8][512][2048]
    bf16*  S    = (bf16*)(ws + 69214208);   // [8][2048][2048]       (67 MB)
    bf16*  Ctx  = (bf16*)(ws + 136323072);  // 16384x512

    // prologue: bf16 conversions
    cvt_f32_bf16<<<8192, 256, 0, stream>>>(x, Xb, 2097152);
    transpose4<<<dim3(8, 8, 4), 256, 0, stream>>>(Wq, Wk, Wv, Wo, Wcat, Wto);
    pack_bias<<<6, 256, 0, stream>>>(bq, bk, bv, bcat);

    const float scale = 0.044194173824159216f;  // 512^-0.5

    // Fused QKV projection: M=16384, N=1536, K=512, split epilogue
    gemm_bt<3, false><<<dim3(12, 128, 1), 256, 0, stream>>>(
        Xb, Wcat, Q, bcat, 1536, 512, 0, 0, 0, 1.0f, 0);

    // S = scale * Q @ K^T, per batch: M=N=2048, K=512; batch<->XCD swizzle
    gemm_bt<0, true><<<2048, 256, 0, stream>>>(
        Q, Kb, S, nullptr, 2048, 512, 2048LL * 512, 2048LL * 512, 2048LL * 2048,
        scale, 16);

    // P = softmax(S) in place
    softmax_rows<<<16384, 256, 0, stream>>>(S);

    // Ctx = P @ V, per batch: M=2048, N=512, K=2048; batch<->XCD swizzle,
    // 4 x-siblings consecutive so the shared S stripe stays in that XCD's L2
    gemm_bt<0, true><<<512, 256, 0, stream>>>(
        S, Vt, Ctx, nullptr, 512, 2048, 2048LL * 2048, 512LL * 2048, 2048LL * 512,
        1.0f, 4);

    // Out = Ctx @ Wo^T + bo: M=16384, N=512, K=512, fp32 out
    gemm_bt<2, false><<<dim3(4, 128, 1), 256, 0, stream>>>(
        Ctx, Wto, out, bo, 512, 512, 0, 0, 0, 1.0f, 0);
}

// Round 3
// 299.172 us; speedup vs baseline: 1.1256x; 1.0587x over previous
//
#include <hip/hip_runtime.h>
#include <hip/hip_bf16.h>
#include <stdint.h>

typedef __bf16 bf16;
typedef __attribute__((ext_vector_type(8))) short short8;
typedef __attribute__((ext_vector_type(4))) float f32x4;
typedef __attribute__((ext_vector_type(4))) bf16 bf16x4;

#define DIM 512
#define NBATCH 8
#define SEQ 2048

// async global->LDS, 16B per lane; LDS dest must be wave-uniform base + lane*16
__device__ __forceinline__ void gld_lds16(const bf16* g, bf16* l) {
    __builtin_amdgcn_global_load_lds(
        (const __attribute__((address_space(1))) void*)g,
        (__attribute__((address_space(3))) void*)l,
        16, 0, 0);
}

// ---------------------------------------------------------------------------
// C = alpha * (A @ Bt^T) + bias  — m97-style bt-GEMM, 128x128 tile, BK=32.
// A:  [M][K] bf16 row-major;  Bt: [N][K] bf16 row-major.
// MODE 0: C bf16 row-major [M][N] (+z*sC)
// MODE 2: C fp32 row-major [M][N]
// MODE 3: QKV split: col<512 -> Q, <1024 -> K, else -> V; all row-major
//         [16384][512], at Cv + {0, 8388608, 16777216} elems.
// MODE 4: C bf16 = exp(alpha*acc); fp32 partial row sums atomicAdd'ed into
//         rsum[z*2048+row]  (softmax without max-subtraction: |logit|<~2).
// MODE 5: C bf16 = acc * (1/rsum[z*2048+row])  (PV + normalize).
// SWIZ 0: plain 3D grid.
// SWIZ 1: 1D grid, bz = g&7 (batch<->XCD), r=g>>3, bx=r%gx, by=r/gx.
// SWIZ 2: 1D grid batchless, xcd=g&7, t=g>>3: column-sibling blocks of one
//         row-stripe stay on one XCD: by = xcd*(total/8/gx) + t/gx, bx=t%gx.
// ---------------------------------------------------------------------------
template <int MODE, int SWIZ>
__global__ __launch_bounds__(256) void gemm_bt(
    const bf16* __restrict__ A, const bf16* __restrict__ Bt,
    void* __restrict__ Cv, const float* __restrict__ bias,
    float* __restrict__ rsum,
    int N, int K, long long sA, long long sB, long long sC, float alpha,
    int gx)
{
    __shared__ bf16 As[128 * 32];
    __shared__ bf16 Bs[128 * 32];

    int bx, by, bz;
    if (SWIZ == 1) {
        const unsigned g = blockIdx.x;
        bz = g & 7;
        const unsigned r = g >> 3;
        bx = r % (unsigned)gx;
        by = r / (unsigned)gx;
    } else if (SWIZ == 2) {
        const unsigned g = blockIdx.x;
        const unsigned xcd = g & 7;
        const unsigned t = g >> 3;
        const unsigned per = (gridDim.x >> 3) / (unsigned)gx;  // stripes per XCD
        by = xcd * per + t / (unsigned)gx;
        bx = t % (unsigned)gx;
        bz = 0;
    } else {
        bx = blockIdx.x; by = blockIdx.y; bz = blockIdx.z;
    }

    const int tid  = threadIdx.x;
    const int lane = tid & 63;
    const int w    = tid >> 6;        // wave 0..3
    const int wr   = w >> 1;          // wave row 0..1  (64-row stripes)
    const int wc   = w & 1;           // wave col 0..1  (64-col stripes)
    const int lm   = lane & 15;       // frag row/col
    const int lk   = lane >> 4;       // frag k-group (0..3)
    const int srow = lane >> 2;       // staging: 4 lanes per row
    const int scol = (lane & 3) * 8;  // staging: 8 bf16 = 16B per lane

    const size_t z = bz;
    const bf16* Ag = A + z * (size_t)sA + (size_t)(by * 128) * K;
    const bf16* Bg = Bt + z * (size_t)sB + (size_t)(bx * 128) * K;

    f32x4 acc[4][4];
#pragma unroll
    for (int i = 0; i < 4; ++i)
#pragma unroll
        for (int j = 0; j < 4; ++j)
            acc[i][j] = (f32x4){0.f, 0.f, 0.f, 0.f};

    for (int kb = 0; kb < K; kb += 32) {
#pragma unroll
        for (int t = 0; t < 2; ++t) {
            const int c = w * 2 + t;          // chunk 0..7 (16 rows each)
            const int r = c * 16 + srow;
            gld_lds16(Ag + (size_t)r * K + kb + scol, &As[r * 32 + scol]);
            gld_lds16(Bg + (size_t)r * K + kb + scol, &Bs[r * 32 + scol]);
        }
        __syncthreads();

        short8 fa[4], fb[4];
#pragma unroll
        for (int i = 0; i < 4; ++i)
            fa[i] = *(const short8*)&As[(wr * 64 + i * 16 + lm) * 32 + lk * 8];
#pragma unroll
        for (int j = 0; j < 4; ++j)
            fb[j] = *(const short8*)&Bs[(wc * 64 + j * 16 + lm) * 32 + lk * 8];
#pragma unroll
        for (int i = 0; i < 4; ++i)
#pragma unroll
            for (int j = 0; j < 4; ++j)
                acc[i][j] = __builtin_amdgcn_mfma_f32_16x16x32_bf16(
                    fa[i], fb[j], acc[i][j], 0, 0, 0);
        __syncthreads();
    }

    // Epilogue. C/D layout: col = lane&15, row = (lane>>4)*4 + reg  (m89/m91)
    const int orow0 = by * 128 + wr * 64;
    const int ocol0 = bx * 128 + wc * 64;

    if (MODE == 4) {
        // exp + partial row sums
#pragma unroll
        for (int i = 0; i < 4; ++i) {
            float psum[4] = {0.f, 0.f, 0.f, 0.f};
#pragma unroll
            for (int j = 0; j < 4; ++j) {
                const int col = ocol0 + j * 16 + lm;
#pragma unroll
                for (int r = 0; r < 4; ++r) {
                    const int row = orow0 + i * 16 + lk * 4 + r;
                    const float e = __expf(acc[i][j][r] * alpha);
                    ((bf16*)Cv)[z * (size_t)sC + (size_t)row * N + col] = (bf16)e;
                    psum[r] += e;
                }
            }
#pragma unroll
            for (int m = 1; m < 16; m <<= 1)
#pragma unroll
                for (int r = 0; r < 4; ++r) psum[r] += __shfl_xor(psum[r], m);
            if (lm == 0) {
#pragma unroll
                for (int r = 0; r < 4; ++r) {
                    const int row = orow0 + i * 16 + lk * 4 + r;
                    atomicAdd(&rsum[z * SEQ + row], psum[r]);
                }
            }
        }
        return;
    }

    if (MODE == 5) {
        // PV + normalize by row sum
#pragma unroll
        for (int i = 0; i < 4; ++i) {
            float inv[4];
#pragma unroll
            for (int r = 0; r < 4; ++r)
                inv[r] = 1.0f / rsum[z * SEQ + orow0 + i * 16 + lk * 4 + r];
#pragma unroll
            for (int j = 0; j < 4; ++j) {
                const int col = ocol0 + j * 16 + lm;
#pragma unroll
                for (int r = 0; r < 4; ++r) {
                    const int row = orow0 + i * 16 + lk * 4 + r;
                    ((bf16*)Cv)[z * (size_t)sC + (size_t)row * N + col] =
                        (bf16)(acc[i][j][r] * inv[r]);
                }
            }
        }
        return;
    }

#pragma unroll
    for (int i = 0; i < 4; ++i) {
#pragma unroll
        for (int j = 0; j < 4; ++j) {
            const int col = ocol0 + j * 16 + lm;
            const float bv = bias ? bias[col] : 0.0f;
#pragma unroll
            for (int r = 0; r < 4; ++r) {
                const int row = orow0 + i * 16 + lk * 4 + r;
                const float v = acc[i][j][r] * alpha + bv;
                if (MODE == 0) {
                    ((bf16*)Cv)[z * (size_t)sC + (size_t)row * N + col] = (bf16)v;
                } else if (MODE == 2) {
                    ((float*)Cv)[z * (size_t)sC + (size_t)row * N + col] = v;
                } else {  // MODE 3: QKV split, all row-major [M][512]
                    bf16* Qp = (bf16*)Cv;
                    size_t off; int cc;
                    if (col < 512)       { off = 0;        cc = col; }
                    else if (col < 1024) { off = 8388608;  cc = col - 512; }
                    else                 { off = 16777216; cc = col - 1024; }
                    Qp[off + (size_t)row * 512 + cc] = (bf16)v;
                }
            }
        }
    }
}

// ---------------------------------------------------------------------------
// V [8][2048][512] bf16 -> Vt [8][512][2048] bf16, 64x64 LDS tiles.
// ---------------------------------------------------------------------------
__global__ __launch_bounds__(256) void transpose_v(
    const bf16* __restrict__ V, bf16* __restrict__ Vt)
{
    __shared__ bf16 tile[64][72];   // [c][r]; row stride 144B (16B-aligned)
    const int b = blockIdx.z, tx = blockIdx.x, ty = blockIdx.y;
    const int t0 = threadIdx.x;
#pragma unroll
    for (int it = 0; it < 2; ++it) {
        const int idx = it * 256 + t0;           // 0..511
        const int r = idx >> 3, c0 = (idx & 7) * 8;
        const uint4 raw = *(const uint4*)&V[((size_t)b * SEQ + ty * 64 + r) * 512 +
                                            tx * 64 + c0];
        const bf16* v8 = (const bf16*)&raw;
#pragma unroll
        for (int j = 0; j < 8; ++j) tile[c0 + j][r] = v8[j];
    }
    __syncthreads();
#pragma unroll
    for (int it = 0; it < 2; ++it) {
        const int idx = it * 256 + t0;
        const int o = idx >> 3, i0 = (idx & 7) * 8;
        const uint4 raw = *(const uint4*)&tile[o][i0];
        *(uint4*)&Vt[((size_t)b * 512 + tx * 64 + o) * SEQ + ty * 64 + i0] = raw;
    }
}

// ---------------------------------------------------------------------------
__global__ __launch_bounds__(256) void cvt_f32_bf16(
    const float* __restrict__ x, bf16* __restrict__ o, int n4)
{
    const int i = blockIdx.x * 256 + threadIdx.x;
    if (i >= n4) return;
    const float4 v = ((const float4*)x)[i];
    bf16x4 b;
    b[0] = (bf16)v.x; b[1] = (bf16)v.y; b[2] = (bf16)v.z; b[3] = (bf16)v.w;
    ((bf16x4*)o)[i] = b;
}

__global__ __launch_bounds__(256) void zero_f32(float* __restrict__ p, int n)
{
    const int i = blockIdx.x * 256 + threadIdx.x;
    if (i < n) p[i] = 0.0f;
}

// Tiled transpose of the four 512x512 fp32 weights -> bf16, transposed.
__global__ __launch_bounds__(256) void transpose4(
    const float* __restrict__ Wq, const float* __restrict__ Wk,
    const float* __restrict__ Wv, const float* __restrict__ Wo,
    bf16* __restrict__ Wcat, bf16* __restrict__ Wto)
{
    __shared__ bf16 tile[64][65];
    const int widx = blockIdx.z;
    const float* W = (widx == 0) ? Wq : (widx == 1) ? Wk : (widx == 2) ? Wv : Wo;
    bf16* dst = (widx < 3) ? (Wcat + (size_t)widx * 512 * 512) : Wto;
    const int tx = blockIdx.x, ty = blockIdx.y;
    const int t0 = threadIdx.x;
#pragma unroll
    for (int it = 0; it < 16; ++it) {
        const int e = it * 256 + t0;
        const int r = e >> 6, c = e & 63;
        tile[r][c] = (bf16)W[(size_t)(ty * 64 + r) * 512 + tx * 64 + c];
    }
    __syncthreads();
#pragma unroll
    for (int it = 0; it < 16; ++it) {
        const int e = it * 256 + t0;
        const int o = e >> 6, i = e & 63;
        dst[(size_t)(tx * 64 + o) * 512 + ty * 64 + i] = tile[i][o];
    }
}

__global__ __launch_bounds__(256) void pack_bias(
    const float* __restrict__ bq, const float* __restrict__ bk,
    const float* __restrict__ bv, float* __restrict__ bcat)
{
    const int i = blockIdx.x * 256 + threadIdx.x;
    if (i >= 1536) return;
    bcat[i] = (i < 512) ? bq[i] : (i < 1024) ? bk[i - 512] : bv[i - 1024];
}

// ---------------------------------------------------------------------------
extern "C" void kernel_launch(void* const* d_in, const int* in_sizes, int n_in,
                              void* d_out, int out_size, void* d_ws, size_t ws_size,
                              hipStream_t stream)
{
    const float* x  = (const float*)d_in[0];
    const float* Wq = (const float*)d_in[1];
    const float* bq = (const float*)d_in[2];
    const float* Wk = (const float*)d_in[3];
    const float* bk = (const float*)d_in[4];
    const float* Wv = (const float*)d_in[5];
    const float* bv = (const float*)d_in[6];
    const float* Wo = (const float*)d_in[7];
    const float* bo = (const float*)d_in[8];
    float* out = (float*)d_out;

    char* ws = (char*)d_ws;
    bf16*  Xb     = (bf16*)(ws);              // 16 MB; dead after QKV GEMM
    bf16*  Ctx    = (bf16*)(ws);              // reuses Xb region (PV output)
    bf16*  Wcat   = (bf16*)(ws + 16777216);   // 1.5 MB (Wq^T|Wk^T|Wv^T)
    bf16*  Wto    = (bf16*)(ws + 18350080);   // 0.5 MB (Wo^T)
    float* bcat   = (float*)(ws + 18874368);  // 6 KB
    float* rowsum = (float*)(ws + 18880512);  // 64 KB fp32 [16384]
    bf16*  Q      = (bf16*)(ws + 20971520);   // 16 MB  (Q|K|V contiguous)
    bf16*  Kb     = (bf16*)(ws + 37748736);   // 16 MB
    bf16*  Vt     = (bf16*)(ws + 54525952);   // 16 MB  [8][512][2048]
    bf16*  V      = (bf16*)(ws + 71303168);   // 16 MB row-major; dead after transpose_v
    bf16*  S      = (bf16*)(ws + 71303168);   // 67 MB, overlaps V (V dead by then)
    // end of usage: 71303168 + 67108864 = 138412032 (~132 MB)

    // prologue
    zero_f32<<<64, 256, 0, stream>>>(rowsum, 16384);
    cvt_f32_bf16<<<8192, 256, 0, stream>>>(x, Xb, 2097152);
    transpose4<<<dim3(8, 8, 4), 256, 0, stream>>>(Wq, Wk, Wv, Wo, Wcat, Wto);
    pack_bias<<<6, 256, 0, stream>>>(bq, bk, bv, bcat);

    const float scale = 0.044194173824159216f;  // 512^-0.5

    // Fused QKV projection: M=16384, N=1536, K=512; V row-major at Q+16M elems.
    // SWIZ=2: 12 column-siblings of each row-stripe pinned to one XCD.
    gemm_bt<3, 2><<<1536, 256, 0, stream>>>(
        Xb, Wcat, Q, bcat, nullptr, 1536, 512, 0, 0, 0, 1.0f, 12);

    // V -> Vt (coalesced LDS-tiled transpose)
    transpose_v<<<dim3(8, 32, 8), 256, 0, stream>>>(Q + 16777216, Vt);

    // S = exp(scale * Q @ K^T) + row sums; per batch M=N=2048, K=512
    gemm_bt<4, 1><<<2048, 256, 0, stream>>>(
        Q, Kb, S, nullptr, rowsum, 2048, 512,
        2048LL * 512, 2048LL * 512, 2048LL * 2048, scale, 16);

    // Ctx = (S @ V) / rowsum: per batch M=2048, N=512, K=2048
    gemm_bt<5, 1><<<512, 256, 0, stream>>>(
        S, Vt, Ctx, nullptr, rowsum, 512, 2048,
        2048LL * 2048, 512LL * 2048, 2048LL * 512, 1.0f, 4);

    // Out = Ctx @ Wo^T + bo: M=16384, N=512, K=512, fp32 out
    gemm_bt<2, 2><<<512, 256, 0, stream>>>(
        Ctx, Wto, out, bo, nullptr, 512, 512, 0, 0, 0, 1.0f, 4);
}